// Round 13
// baseline (379.698 us; speedup 1.0000x reference)
//
#include <hip/hip_runtime.h>
#include <math.h>

static constexpr int kN   = 50000;
static constexpr int kB   = 500;
static constexpr int kNPG = 100;
static constexpr int kEPG = 1600;
static constexpr int kESG = 800;
static constexpr int kF0  = 128;
static constexpr int kH1  = 256;
static constexpr int kH2  = 128;
#define BN_EPS 1e-5f

typedef _Float16 half8 __attribute__((ext_vector_type(8)));
typedef __attribute__((ext_vector_type(4))) float f32x4;

// LDS layout for gcn_agg (bytes):
//  cnt32 u32[112][33]  @ 0       (14784 B)  — packed u8 edge counts
//  Adh   fp16[112][136] @ 14784  (30464 B)  — normalized adjacency
//  Hst   fp16[128][136] @ 45248  (34816 B)  — W=128 only: H transposed
static constexpr int kCntW = 33;
static constexpr int kAhS  = 136;
static constexpr unsigned kAggLds256 = 45248;   // 3 blocks/CU
static constexpr unsigned kAggLds128 = 80064;   // 2 blocks/CU

// ============ weight prep: W[K][Nc] f32 -> Wt[(kg*Nc + c)*8 + e] fp16 ============
__global__ __launch_bounds__(256)
void wprep_k(const float* __restrict__ s0, const float* __restrict__ s1,
             const float* __restrict__ s2, const float* __restrict__ s3,
             const float* __restrict__ s4, _Float16* __restrict__ d)
{
  int seg = blockIdx.x >> 7;
  int idx = (blockIdx.x & 127) * 256 + threadIdx.x;   // 0..32767
  const float* S; int Nc;
  switch (seg) {
    case 0: S = s0; Nc = 256; break;
    case 1: S = s1; Nc = 128; break;
    case 2: S = s2; Nc = 256; break;
    case 3: S = s3; Nc = 128; break;
    default: S = s4; Nc = 256; break;
  }
  int e = idx & 7, t = idx >> 3;
  int c = t % Nc, kg = t / Nc;
  d[seg * 32768 + idx] = (_Float16)S[(size_t)(kg * 8 + e) * Nc + c];
}

// ================= direct-global fp16 MFMA GEMM (no LDS, no barriers) =================
// Wave tile 32x64. K and NC are COMPILE-TIME (r12 lesson: runtime K blocked
// unrolling -> load/MFMA lockstep, 40 VGPR, no pipelining, 26% HBM at any
// occupancy). Full unroll lets the compiler hoist/pipeline loads across
// k-steps. blockIdx.z selects (A0,C0)/(A1,C1) for batched pos/neg.
// NOTE: A and C must NOT alias (cross-block race — r2..r4 lesson).
template<int ACT, int TRANS, int K, int NC, typename AT, typename OT>
__global__ __launch_bounds__(256)
void gemm_direct_k(const AT* __restrict__ A0, const AT* __restrict__ A1,
                   const _Float16* __restrict__ Wt, const float* __restrict__ tr,
                   OT* __restrict__ C0, OT* __restrict__ C1, int M)
{
  const AT* A = blockIdx.z ? A1 : A0;
  OT* C = blockIdx.z ? C1 : C0;
  const int tid = threadIdx.x;
  const int lane = tid & 63;
  const int l15 = lane & 15, lg = lane >> 4;
  const int wave = tid >> 6;
  const int wm = wave >> 1, wn = wave & 1;
  const int bm = blockIdx.x * 64;
  const int bn = blockIdx.y * 128;
  f32x4 acc[2][4];
#pragma unroll
  for (int m = 0; m < 2; ++m)
#pragma unroll
    for (int n = 0; n < 4; ++n) acc[m][n] = (f32x4){0.f, 0.f, 0.f, 0.f};

  int arow[2]; bool mok[2];
#pragma unroll
  for (int m = 0; m < 2; ++m) {
    arow[m] = bm + wm * 32 + m * 16 + l15;
    mok[m] = arow[m] < M;
  }
  const int bcol = bn + wn * 64 + l15;

#pragma unroll
  for (int k0 = 0; k0 < K; k0 += 32) {
    const int kb = k0 + lg * 8;
    half8 bF[4];
#pragma unroll
    for (int n = 0; n < 4; ++n)
      bF[n] = *(const half8*)&Wt[((size_t)((k0 >> 3) + lg) * NC + bcol + n * 16) * 8];
    half8 aF[2];
#pragma unroll
    for (int m = 0; m < 2; ++m) {
      half8 sa;
#pragma unroll
      for (int j = 0; j < 8; ++j) sa[j] = (_Float16)0.f;
      if (mok[m]) {
        if constexpr (sizeof(AT) == 4) {
          const float* ap = (const float*)A + (size_t)arow[m] * K + kb;
          float4 u0 = *(const float4*)ap, u1 = *(const float4*)(ap + 4);
          float va[8] = {u0.x, u0.y, u0.z, u0.w, u1.x, u1.y, u1.z, u1.w};
          if constexpr (TRANS) {
#pragma unroll
            for (int j = 0; j < 8; ++j) va[j] = (va[j] - tr[kb + j]) * tr[256 + kb + j];
          }
#pragma unroll
          for (int j = 0; j < 8; ++j) sa[j] = (_Float16)va[j];
        } else {
          half8 h = *(const half8*)((const _Float16*)A + (size_t)arow[m] * K + kb);
          if constexpr (TRANS) {
#pragma unroll
            for (int j = 0; j < 8; ++j)
              sa[j] = (_Float16)(((float)h[j] - tr[kb + j]) * tr[256 + kb + j]);
          } else {
            sa = h;
          }
        }
      }
      aF[m] = sa;
    }
#pragma unroll
    for (int m = 0; m < 2; ++m)
#pragma unroll
      for (int n = 0; n < 4; ++n)
        acc[m][n] = __builtin_amdgcn_mfma_f32_16x16x32_f16(aF[m], bF[n], acc[m][n], 0, 0, 0);
  }
  // epilogue: C/D layout col=lane&15, row=(lane>>4)*4+q
#pragma unroll
  for (int m = 0; m < 2; ++m) {
    int row_b = bm + wm * 32 + m * 16 + lg * 4;
#pragma unroll
    for (int q = 0; q < 4; ++q) {
      int row = row_b + q;
      if (row >= M) continue;
#pragma unroll
      for (int n = 0; n < 4; ++n) {
        float v = acc[m][n][q];
        if (ACT == 1) v = fmaxf(v, 0.f);
        else if (ACT == 2) v = 1.f / (1.f + expf(-v));
        C[(size_t)row * NC + bn + wn * 64 + n * 16 + l15] = (OT)v;
      }
    }
  }
}

// ======================= small-M tiled f32 GEMM (M<=1000 paths) =======================
template<int ACT>
__global__ __launch_bounds__(256)
void gemm_k(const float* __restrict__ A, const float* __restrict__ W,
            const float* __restrict__ bias, float* __restrict__ C,
            int M, int K, int Nc)
{
  __shared__ float As[32][136];
  __shared__ float Ws[32][68];
  const int tid = threadIdx.x;
  const int bm = blockIdx.x * 128;
  const int bn = blockIdx.y * 64;
  const int tm = (tid & 15) * 8;
  const int tn = (tid >> 4) * 4;
  float acc[8][4];
#pragma unroll
  for (int i = 0; i < 8; ++i)
#pragma unroll
    for (int j = 0; j < 4; ++j) acc[i][j] = 0.f;

  for (int k0 = 0; k0 < K; k0 += 32) {
#pragma unroll
    for (int l = 0; l < 4; ++l) {
      int idx = tid + l * 256;
      int r = idx >> 3;
      int kq = (idx & 7) << 2;
      int gr = bm + r;
      float4 v = make_float4(0.f, 0.f, 0.f, 0.f);
      if (gr < M) v = *(const float4*)&A[(size_t)gr * K + k0 + kq];
      As[kq + 0][r] = v.x; As[kq + 1][r] = v.y;
      As[kq + 2][r] = v.z; As[kq + 3][r] = v.w;
    }
#pragma unroll
    for (int l = 0; l < 2; ++l) {
      int idx = tid + l * 256;
      int r = idx >> 4;
      int nq = (idx & 15) << 2;
      *(float4*)&Ws[r][nq] = *(const float4*)&W[(size_t)(k0 + r) * Nc + bn + nq];
    }
    __syncthreads();
#pragma unroll
    for (int kk = 0; kk < 32; ++kk) {
      float4 a0 = *(float4*)&As[kk][tm];
      float4 a1 = *(float4*)&As[kk][tm + 4];
      float4 w4 = *(float4*)&Ws[kk][tn];
      float am[8] = {a0.x, a0.y, a0.z, a0.w, a1.x, a1.y, a1.z, a1.w};
      float wn4[4] = {w4.x, w4.y, w4.z, w4.w};
#pragma unroll
      for (int i = 0; i < 8; ++i)
#pragma unroll
        for (int j = 0; j < 4; ++j) acc[i][j] += am[i] * wn4[j];
    }
    __syncthreads();
  }
  float4 bv = make_float4(0.f, 0.f, 0.f, 0.f);
  if (bias) bv = *(const float4*)&bias[bn + tn];
#pragma unroll
  for (int i = 0; i < 8; ++i) {
    int row = bm + tm + i;
    if (row >= M) break;
    float o0 = acc[i][0] + bv.x, o1 = acc[i][1] + bv.y;
    float o2 = acc[i][2] + bv.z, o3 = acc[i][3] + bv.w;
    if (ACT == 1) {
      o0 = fmaxf(o0, 0.f); o1 = fmaxf(o1, 0.f);
      o2 = fmaxf(o2, 0.f); o3 = fmaxf(o3, 0.f);
    } else if (ACT == 2) {
      o0 = 1.f / (1.f + expf(-o0)); o1 = 1.f / (1.f + expf(-o1));
      o2 = 1.f / (1.f + expf(-o2)); o3 = 1.f / (1.f + expf(-o3));
    }
    *(float4*)&C[(size_t)row * Nc + bn + tn] = make_float4(o0, o1, o2, o3);
  }
}

// ================= per-graph GCN aggregation, MFMA (fused tails) =================
// Integer-count adjacency build (deterministic), fp16 Adh; W=128 stages H
// transposed in LDS. See r10/r11 notes. blockIdx.y selects pos/neg.
template<int W, int ACT, int SEGBN, int L2N, int POOL, int STATS, int MAXP, typename OT>
__global__ __launch_bounds__(512)
void gcn_agg_k(const _Float16* __restrict__ H0, const _Float16* __restrict__ H1,
               const int* __restrict__ src0, const int* __restrict__ src1,
               const int* __restrict__ dst0, const int* __restrict__ dst1,
               const float* __restrict__ bias,
               OT* __restrict__ OUT0, OT* __restrict__ OUT1, int epg,
               const float* __restrict__ NOI, float* __restrict__ PST,
               float* __restrict__ ZG, float* __restrict__ ZZ)
{
  extern __shared__ __align__(16) unsigned lds_u[];
  unsigned* cnt32 = lds_u;                                   // [112][33] u32
  _Float16* Adh = (_Float16*)(lds_u + 112 * kCntW);          // [112][136]
  _Float16* Hst = (_Float16*)((char*)lds_u + 45248);         // [128][136] (W=128)
  float* scr = (float*)lds_u;                                // post-MFMA scratch
  __shared__ int scnt[kNPG];
  __shared__ float sdinv[kNPG];
  const _Float16* H = blockIdx.y ? H1 : H0;
  const int* srcI = blockIdx.y ? src1 : src0;
  const int* dstI = blockIdx.y ? dst1 : dst0;
  OT* OUT = blockIdx.y ? OUT1 : OUT0;
  const int g = blockIdx.x, tid = threadIdx.x;
  const int base = g * kNPG;
  const size_t ebase = (size_t)g * epg;
  const int lane = tid & 63, wv = tid >> 6;
  const int l15 = lane & 15, lg = lane >> 4;

  for (int i = tid; i < 112 * kCntW; i += 512) cnt32[i] = 0u;
  if constexpr (W == 128) {
    for (int i = tid; i < 128 * 18; i += 512) {
      int c = i / 18, w = i - c * 18;
      ((unsigned*)&Hst[c * kAhS + 100])[w] = 0u;
    }
  }
  if (tid < kNPG) scnt[tid] = 0;
  __syncthreads();
  for (int e = tid; e < epg; e += 512) {
    int s = srcI[ebase + e] - base;
    int d = dstI[ebase + e] - base;
    atomicAdd(&scnt[d], 1);
    atomicAdd(&cnt32[d * kCntW + (s >> 2)], 1u << (8 * (s & 3)));
  }
  __syncthreads();
  if (tid < kNPG) sdinv[tid] = rsqrtf((float)scnt[tid] + 1.f);
  __syncthreads();
  for (int i = tid; i < 112 * kAhS; i += 512) {
    int d = i / kAhS, s = i - d * kAhS;
    float v = 0.f;
    if (d < 100 && s < 100) {
      unsigned w = cnt32[d * kCntW + (s >> 2)];
      unsigned c = (w >> (8 * (s & 3))) & 0xFFu;
      c += (s == d) ? 1u : 0u;
      v = (float)c * sdinv[s] * sdinv[d];
    }
    Adh[i] = (_Float16)v;
  }
  if constexpr (W == 128) {
    const int c = tid & 127;
    for (int j = tid >> 7; j < 100; j += 4)
      Hst[c * kAhS + j] = H[(size_t)(base + j) * 128 + c];
  }
  __syncthreads();

  if constexpr (W == 256) {
    const int cbase = wv * 32;
    f32x4 acc[7][2];
#pragma unroll
    for (int mt = 0; mt < 7; ++mt) {
      acc[mt][0] = (f32x4){0.f, 0.f, 0.f, 0.f};
      acc[mt][1] = (f32x4){0.f, 0.f, 0.f, 0.f};
    }
#pragma unroll
    for (int k0 = 0; k0 < 128; k0 += 32) {
      const int kb = k0 + lg * 8;
      half8 bF[2];
#pragma unroll
      for (int t = 0; t < 2; ++t) {
        int col = cbase + t * 16 + l15;
#pragma unroll
        for (int e = 0; e < 8; ++e) {
          int row = min(base + kb + e, kN - 1);   // clamp: Adh=0 past 100
          bF[t][e] = H[(size_t)row * W + col];
        }
      }
#pragma unroll
      for (int mt = 0; mt < 7; ++mt) {
        half8 aF = *(const half8*)&Adh[(mt * 16 + l15) * kAhS + kb];
        acc[mt][0] = __builtin_amdgcn_mfma_f32_16x16x32_f16(aF, bF[0], acc[mt][0], 0, 0, 0);
        acc[mt][1] = __builtin_amdgcn_mfma_f32_16x16x32_f16(aF, bF[1], acc[mt][1], 0, 0, 0);
      }
    }
    float bv0 = bias ? bias[cbase + l15] : 0.f;
    float bv1 = bias ? bias[cbase + 16 + l15] : 0.f;
#pragma unroll
    for (int mt = 0; mt < 7; ++mt)
#pragma unroll
      for (int q = 0; q < 4; ++q) {
        float v0 = acc[mt][0][q] + bv0, v1 = acc[mt][1][q] + bv1;
        if (ACT == 1) { v0 = fmaxf(v0, 0.f); v1 = fmaxf(v1, 0.f); }
        acc[mt][0][q] = v0; acc[mt][1][q] = v1;
      }
    if constexpr (SEGBN || STATS) {
      float s0 = 0.f, s20 = 0.f, s1 = 0.f, s21 = 0.f;
#pragma unroll
      for (int mt = 0; mt < 7; ++mt)
#pragma unroll
        for (int q = 0; q < 4; ++q) {
          int row = mt * 16 + lg * 4 + q;
          if (row < 100) {
            float v0 = acc[mt][0][q], v1 = acc[mt][1][q];
            s0 += v0; s20 += v0 * v0; s1 += v1; s21 += v1 * v1;
          }
        }
      s0 += __shfl_xor(s0, 16, 64);  s0 += __shfl_xor(s0, 32, 64);
      s20 += __shfl_xor(s20, 16, 64); s20 += __shfl_xor(s20, 32, 64);
      s1 += __shfl_xor(s1, 16, 64);  s1 += __shfl_xor(s1, 32, 64);
      s21 += __shfl_xor(s21, 16, 64); s21 += __shfl_xor(s21, 32, 64);
      if constexpr (STATS) {
        if (lg == 0) {
          PST[(size_t)g * 512 + cbase + l15] = s0;
          PST[(size_t)g * 512 + 256 + cbase + l15] = s20;
          PST[(size_t)g * 512 + cbase + 16 + l15] = s1;
          PST[(size_t)g * 512 + 256 + cbase + 16 + l15] = s21;
        }
      }
      if constexpr (SEGBN) {
        float m0 = s0 / 100.f, r0 = rsqrtf(s20 / 100.f - m0 * m0 + BN_EPS);
        float m1 = s1 / 100.f, r1 = rsqrtf(s21 / 100.f - m1 * m1 + BN_EPS);
#pragma unroll
        for (int mt = 0; mt < 7; ++mt)
#pragma unroll
          for (int q = 0; q < 4; ++q) {
            acc[mt][0][q] = (acc[mt][0][q] - m0) * r0;
            acc[mt][1][q] = (acc[mt][1][q] - m1) * r1;
          }
      }
    }
#pragma unroll
    for (int mt = 0; mt < 7; ++mt)
#pragma unroll
      for (int q = 0; q < 4; ++q) {
        int row = mt * 16 + lg * 4 + q;
        if (row < 100) {
          OUT[(size_t)(base + row) * W + cbase + l15] = (OT)acc[mt][0][q];
          OUT[(size_t)(base + row) * W + cbase + 16 + l15] = (OT)acc[mt][1][q];
        }
      }
  } else {
    const int mt = wv;                 // waves 0..6 active
    f32x4 acc[8];
#pragma unroll
    for (int nt = 0; nt < 8; ++nt) acc[nt] = (f32x4){0.f, 0.f, 0.f, 0.f};
    if (mt < 7) {
#pragma unroll
      for (int k0 = 0; k0 < 128; k0 += 32) {
        const int kb = k0 + lg * 8;
        half8 aF = *(const half8*)&Adh[(mt * 16 + l15) * kAhS + kb];
#pragma unroll
        for (int nt = 0; nt < 8; ++nt) {
          half8 bF = *(const half8*)&Hst[(nt * 16 + l15) * kAhS + kb];
          acc[nt] = __builtin_amdgcn_mfma_f32_16x16x32_f16(aF, bF, acc[nt], 0, 0, 0);
        }
      }
#pragma unroll
      for (int nt = 0; nt < 8; ++nt) {
        float bvn = bias ? bias[nt * 16 + l15] : 0.f;
#pragma unroll
        for (int q = 0; q < 4; ++q) {
          float v = acc[nt][q] + bvn;
          if (ACT == 1) v = fmaxf(v, 0.f);
          acc[nt][q] = v;
        }
      }
      if constexpr (L2N) {
#pragma unroll
        for (int q = 0; q < 4; ++q) {
          float ss = 0.f;
#pragma unroll
          for (int nt = 0; nt < 8; ++nt) ss += acc[nt][q] * acc[nt][q];
          ss += __shfl_xor(ss, 1, 64); ss += __shfl_xor(ss, 2, 64);
          ss += __shfl_xor(ss, 4, 64); ss += __shfl_xor(ss, 8, 64);
          float inv = 1.f / fmaxf(sqrtf(ss), 1e-12f);
#pragma unroll
          for (int nt = 0; nt < 8; ++nt) acc[nt][q] *= inv;
        }
      }
      if constexpr (!POOL) {
#pragma unroll
        for (int nt = 0; nt < 8; ++nt)
#pragma unroll
          for (int q = 0; q < 4; ++q) {
            int row = mt * 16 + lg * 4 + q;
            if (row < 100)
              OUT[(size_t)(base + row) * W + nt * 16 + l15] = (OT)acc[nt][q];
          }
      }
    }
    if constexpr (POOL) {
      float ps[8];
#pragma unroll
      for (int nt = 0; nt < 8; ++nt) ps[nt] = 0.f;
      if (mt < 7) {
#pragma unroll
        for (int nt = 0; nt < 8; ++nt)
#pragma unroll
          for (int q = 0; q < 4; ++q) {
            int row = mt * 16 + lg * 4 + q;
            if (row < 100) ps[nt] += acc[nt][q];
          }
      }
#pragma unroll
      for (int nt = 0; nt < 8; ++nt) {
        ps[nt] += __shfl_xor(ps[nt], 16, 64);
        ps[nt] += __shfl_xor(ps[nt], 32, 64);
      }
      __syncthreads();                  // cnt32/Adh dead -> scratch
      if (mt < 7 && lg == 0)
#pragma unroll
        for (int nt = 0; nt < 8; ++nt) scr[wv * 128 + nt * 16 + l15] = ps[nt];
      __syncthreads();
      if (tid < 128) {
        float s = 0.f;
        for (int w2 = 0; w2 < 7; ++w2) s += scr[w2 * 128 + tid];
        OUT[(size_t)g * W + tid] = (OT)(s / 100.f);
      }
    }
    if constexpr (MAXP) {
      float m1[8], m2[8];
#pragma unroll
      for (int nt = 0; nt < 8; ++nt) { m1[nt] = -INFINITY; m2[nt] = -INFINITY; }
      if (mt < 7) {
#pragma unroll
        for (int nt = 0; nt < 8; ++nt)
#pragma unroll
          for (int q = 0; q < 4; ++q) {
            int row = mt * 16 + lg * 4 + q;
            if (row < 100) {
              float zv = acc[nt][q];
              float nv = NOI[(size_t)(base + row) * 128 + nt * 16 + l15];
              m1[nt] = fmaxf(m1[nt], zv);
              m2[nt] = fmaxf(m2[nt], zv + nv);
            }
          }
#pragma unroll
        for (int nt = 0; nt < 8; ++nt) {
          m1[nt] = fmaxf(m1[nt], __shfl_xor(m1[nt], 16, 64));
          m1[nt] = fmaxf(m1[nt], __shfl_xor(m1[nt], 32, 64));
          m2[nt] = fmaxf(m2[nt], __shfl_xor(m2[nt], 16, 64));
          m2[nt] = fmaxf(m2[nt], __shfl_xor(m2[nt], 32, 64));
        }
      }
      __syncthreads();                  // cnt32/Adh dead -> scratch
      if (mt < 7 && lg == 0)
#pragma unroll
        for (int nt = 0; nt < 8; ++nt) {
          scr[wv * 128 + nt * 16 + l15] = m1[nt];
          scr[1024 + wv * 128 + nt * 16 + l15] = m2[nt];
        }
      __syncthreads();
      if (tid < 128) {
        float a = -INFINITY, b = -INFINITY;
        for (int w2 = 0; w2 < 7; ++w2) {
          a = fmaxf(a, scr[w2 * 128 + tid]);
          b = fmaxf(b, scr[1024 + w2 * 128 + tid]);
        }
        ZG[(size_t)g * 128 + tid] = a;
        ZZ[(size_t)g * 128 + tid] = a;
        ZZ[(size_t)(500 + g) * 128 + tid] = b;
      }
    }
  }
}

// ============ BN finalize: sum 500 per-graph partials (fixed order) ============
__global__ __launch_bounds__(256)
void bn_red_k(const float* __restrict__ P, float* __restrict__ stats)
{
  const int c = threadIdx.x;
  float s = 0.f, s2 = 0.f;
  for (int b = 0; b < 500; ++b) {
    s  += P[(size_t)b * 512 + c];
    s2 += P[(size_t)b * 512 + 256 + c];
  }
  float m = s / (float)kN;
  float v = s2 / (float)kN - m * m;
  stats[512 + c] = m;
  stats[768 + c] = rsqrtf(v + BN_EPS);
}

// column-parallel BN, in place (target path)
__global__ __launch_bounds__(64)
void bn_cols_k(float* __restrict__ X, int rows, int cols)
{
  const int c = blockIdx.x, t = threadIdx.x;
  float s = 0.f, s2 = 0.f;
  for (int r = t; r < rows; r += 64) {
    float v = X[(size_t)r * cols + c];
    s += v; s2 += v * v;
  }
#pragma unroll
  for (int o = 32; o; o >>= 1) { s += __shfl_xor(s, o, 64); s2 += __shfl_xor(s2, o, 64); }
  float m = s / (float)rows;
  float var = s2 / (float)rows - m * m;
  float rinv = rsqrtf(var + BN_EPS);
  for (int r = t; r < rows; r += 64)
    X[(size_t)r * cols + c] = (X[(size_t)r * cols + c] - m) * rinv;
}

// row-wise L2 normalize (128 cols) — target path
__global__ __launch_bounds__(256)
void l2n_k(const float* __restrict__ X, float* __restrict__ Y, int rows)
{
  const int w = threadIdx.x >> 6, lane = threadIdx.x & 63;
  const int row = blockIdx.x * 4 + w;
  if (row >= rows) return;
  float2 v = *(const float2*)&X[(size_t)row * kH2 + lane * 2];
  float ss = v.x * v.x + v.y * v.y;
#pragma unroll
  for (int o = 32; o; o >>= 1) ss += __shfl_xor(ss, o, 64);
  float inv = 1.f / fmaxf(sqrtf(ss), 1e-12f);
  *(float2*)&Y[(size_t)row * kH2 + lane * 2] = make_float2(v.x * inv, v.y * inv);
}

// =========================================================================
extern "C" void kernel_launch(void* const* d_in, const int* in_sizes, int n_in,
                              void* d_out, int out_size, void* d_ws, size_t ws_size,
                              hipStream_t stream)
{
  const float* x        = (const float*)d_in[0];
  const int*   srcI     = (const int*)d_in[1];
  const int*   dstI     = (const int*)d_in[2];
  const float* pos_x    = (const float*)d_in[4];
  const int*   psrc     = (const int*)d_in[5];
  const int*   pdst     = (const int*)d_in[6];
  const float* neg_x    = (const float*)d_in[8];
  const int*   nsrc     = (const int*)d_in[9];
  const int*   ndst     = (const int*)d_in[10];
  const float* target_x = (const float*)d_in[12];
  const float* noise    = (const float*)d_in[13];
  const float* W_enc1   = (const float*)d_in[14];
  const float* b_enc1   = (const float*)d_in[15];
  const float* W_enc2   = (const float*)d_in[16];
  const float* b_enc2   = (const float*)d_in[17];
  const float* W_dec1   = (const float*)d_in[18];
  const float* W_dec2   = (const float*)d_in[19];
  const float* Wn1      = (const float*)d_in[20];
  const float* bn1      = (const float*)d_in[21];
  const float* Wn2      = (const float*)d_in[22];
  const float* bn2      = (const float*)d_in[23];
  const float* Ws1      = (const float*)d_in[24];
  const float* bs1      = (const float*)d_in[25];
  const float* Wp1      = (const float*)d_in[26];
  const float* bp1      = (const float*)d_in[27];
  const float* Wp2      = (const float*)d_in[28];
  const float* bp2      = (const float*)d_in[29];

  float* out  = (float*)d_out;
  float* o_z   = out;                 // N x 128
  float* o_zg  = out + 6400000;       // 500 x 128
  float* o_xr  = out + 6464000;       // N x 128
  float* o_pos = out + 12864000;      // 500 x 128
  float* o_neg = out + 12928000;
  float* o_zgm = out + 12992000;      // o_zgm||o_zpm contiguous 1000 x 128
  float* o_tz  = out + 13120000;

  // WORKSPACE MAP (float offsets). Four 6.4M-float quarters Q0..Q3 hold fp16
  // N x 256 regions; every kernel reads one region and writes another
  // (r2-r4 race lesson). Time-multiplexed aliases audited per launch below.
  float* ws = (float*)d_ws;
  _Float16* hA    = (_Float16*)ws;                    // Q0
  _Float16* hC    = (_Float16*)ws;                    // Q0 (N x 128)
  _Float16* hDec  = (_Float16*)ws;                    // Q0
  _Float16* hAn   = (_Float16*)(ws + 6400000);        // Q1
  _Float16* hCn   = (_Float16*)(ws + 6400000);        // Q1
  _Float16* hB    = (_Float16*)(ws + 12800000);       // Q2
  _Float16* hBn   = (_Float16*)(ws + 19200000);       // Q3
  float* pstat = ws + 19200000;                       // Q3 (main-time only)
  _Float16* hWt   = (_Float16*)(ws + 25600000);       // 163840 fp16
  float* stats = ws + 25700000;                       // 1024
  float* zz    = ws + 6400000;                        // Q1 (main/proj-time)
  float* t1000 = ws + 6600000;                        // Q1 (proj-time)
  float* t1    = ws + 4000000;                        // Q0 tail (target-time)
  float* t2    = ws + 4200000;                        // Q0 tail (target-time)
  if (ws_size < (size_t)(25921024) * sizeof(float)) return;

  _Float16* WtEnc1 = hWt;
  _Float16* WtEnc2 = hWt + 32768;
  _Float16* WtDec1 = hWt + 65536;
  _Float16* WtDec2 = hWt + 98304;
  _Float16* WtS1   = hWt + 131072;

  (void)hipFuncSetAttribute((const void*)gcn_agg_k<128, 0, 0, 1, 0, 0, 1, float>,
      hipFuncAttributeMaxDynamicSharedMemorySize, kAggLds128);
  (void)hipFuncSetAttribute((const void*)gcn_agg_k<128, 0, 0, 1, 1, 0, 0, float>,
      hipFuncAttributeMaxDynamicSharedMemorySize, kAggLds128);

  const dim3 gB1(782, 2, 1);   // M=50000 (64-row tiles), Nc=256, single
  const dim3 gC1(782, 1, 1);   // Nc=128, single
  const dim3 gB2(782, 2, 2);   // batched pos+neg
  const dim3 gC2(782, 1, 2);
  auto gg = [](int M, int Nc) {
    return dim3((unsigned)((M + 127) / 128), (unsigned)(Nc / 64), 1);
  };

  // ---------------- weight prep ----------------
  wprep_k<<<640, 256, 0, stream>>>(W_enc1, W_enc2, W_dec1, W_dec2, Ws1, hWt);

  // ---------------- main encode ----------------
  gemm_direct_k<0, 0, 128, 256, float, _Float16><<<gB1, 256, 0, stream>>>(x, x, WtEnc1, nullptr, hA, hA, kN);
  // agg256+STATS: reads hA(Q0) -> writes hB(Q2) + pstat(Q3)
  gcn_agg_k<256, 1, 0, 0, 0, 1, 0, _Float16><<<dim3(kB, 1), 512, kAggLds256, stream>>>(
      hA, hA, srcI, srcI, dstI, dstI, b_enc1, hB, hB, kEPG, nullptr, pstat, nullptr, nullptr);
  bn_red_k<<<1, 256, 0, stream>>>(pstat, stats);
  // G2+BN: reads hB(Q2)+stats -> writes hC(Q0)
  gemm_direct_k<0, 1, 256, 128, _Float16, _Float16><<<gC1, 256, 0, stream>>>(hB, hB, WtEnc2, stats + 512, hC, hC, kN);
  // agg128+L2N+MAXP: reads hC(Q0)+noise -> writes o_z, o_zg, zz(Q1)
  gcn_agg_k<128, 0, 0, 1, 0, 0, 1, float><<<dim3(kB, 1), 512, kAggLds128, stream>>>(
      hC, hC, srcI, srcI, dstI, dstI, b_enc2, o_z, o_z, kEPG, noise, nullptr, o_zg, zz);
  // decode: o_z(d_out) -> hDec(Q0) -> o_xr(d_out)
  gemm_direct_k<1, 0, 128, 256, float, _Float16><<<gB1, 256, 0, stream>>>(o_z, o_z, WtDec1, nullptr, hDec, hDec, kN);
  gemm_direct_k<2, 0, 256, 128, _Float16, float><<<gC1, 256, 0, stream>>>(hDec, hDec, WtDec2, nullptr, o_xr, o_xr, kN);
  // merged projection heads: zz(Q1) -> t1000(Q1') -> o_zgm||o_zpm
  gemm_k<1><<<gg(1000, kH2), 256, 0, stream>>>(zz, Wp1, bp1, t1000, 1000, kH2, kH2);
  gemm_k<0><<<gg(1000, kH2), 256, 0, stream>>>(t1000, Wp2, bp2, o_zgm, 1000, kH2, kH2);

  // ---------------- pos + neg, batched ----------------
  gemm_direct_k<0, 0, 128, 256, float, _Float16><<<gB2, 256, 0, stream>>>(pos_x, neg_x, WtS1, nullptr, hA, hAn, kN);
  gcn_agg_k<256, 1, 1, 0, 0, 0, 0, _Float16><<<dim3(kB, 2), 512, kAggLds256, stream>>>(
      hA, hAn, psrc, nsrc, pdst, ndst, bs1, hB, hBn, kESG, nullptr, nullptr, nullptr, nullptr);
  gemm_direct_k<0, 0, 256, 128, _Float16, _Float16><<<gC2, 256, 0, stream>>>(hB, hBn, WtEnc2, nullptr, hC, hCn, kN);
  gcn_agg_k<128, 0, 0, 1, 1, 0, 0, float><<<dim3(kB, 2), 512, kAggLds128, stream>>>(
      hC, hCn, psrc, nsrc, pdst, ndst, b_enc2, o_pos, o_neg, kESG, nullptr, nullptr, nullptr, nullptr);

  // ---------------- target node encoder ----------------
  gemm_k<1><<<gg(kB, kH1), 256, 0, stream>>>(target_x, Wn1, bn1, t1, kB, kF0, kH1);
  bn_cols_k<<<256, 64, 0, stream>>>(t1, kB, kH1);
  gemm_k<0><<<gg(kB, kH2), 256, 0, stream>>>(t1, Wn2, bn2, t2, kB, kH1, kH2);
  l2n_k<<<125, 256, 0, stream>>>(t2, o_tz, kB);

  (void)in_sizes; (void)n_in; (void)out_size;
}

// Round 14
// 375.309 us; speedup vs baseline: 1.0117x; 1.0117x over previous
//
#include <hip/hip_runtime.h>
#include <math.h>

static constexpr int kN   = 50000;
static constexpr int kB   = 500;
static constexpr int kNPG = 100;
static constexpr int kEPG = 1600;
static constexpr int kESG = 800;
static constexpr int kF0  = 128;
static constexpr int kH1  = 256;
static constexpr int kH2  = 128;
#define BN_EPS 1e-5f

typedef _Float16 half8 __attribute__((ext_vector_type(8)));
typedef __attribute__((ext_vector_type(4))) float f32x4;

// LDS layout for gcn_agg (bytes):
//  cnt32 u32[112][33]  @ 0       (14784 B)  — packed u8 edge counts
//  Adh   fp16[112][136] @ 14784  (30464 B)  — normalized adjacency
//  Hst   fp16[128][136] @ 45248  (34816 B)  — W=128 only: H transposed
static constexpr int kCntW = 33;
static constexpr int kAhS  = 136;
static constexpr unsigned kAggLds256 = 45248;   // 3 blocks/CU
static constexpr unsigned kAggLds128 = 80064;   // 2 blocks/CU

// ============ weight prep: W[K][Nc] f32 -> Wt[(kg*Nc + c)*8 + e] fp16 ============
__global__ __launch_bounds__(256)
void wprep_k(const float* __restrict__ s0, const float* __restrict__ s1,
             const float* __restrict__ s2, const float* __restrict__ s3,
             const float* __restrict__ s4, _Float16* __restrict__ d)
{
  int seg = blockIdx.x >> 7;
  int idx = (blockIdx.x & 127) * 256 + threadIdx.x;   // 0..32767
  const float* S; int Nc;
  switch (seg) {
    case 0: S = s0; Nc = 256; break;
    case 1: S = s1; Nc = 128; break;
    case 2: S = s2; Nc = 256; break;
    case 3: S = s3; Nc = 128; break;
    default: S = s4; Nc = 256; break;
  }
  int e = idx & 7, t = idx >> 3;
  int c = t % Nc, kg = t / Nc;
  d[seg * 32768 + idx] = (_Float16)S[(size_t)(kg * 8 + e) * Nc + c];
}

// ================= direct-global fp16 MFMA GEMM (no LDS, no barriers) =================
// Wave tile 32x64. K/NC compile-time. r13 lesson: guarded A-loads +
// compiler-chosen schedule gave NO cross-k pipelining (VGPR 48, 27% HBM at
// any occupancy). This version: (a) A-row index CLAMPED to M-1 so all loads
// are unconditional straight-line (stores stay guarded; M-dim has no
// cross-row mixing, so clamped rows only affect their own discarded rows),
// (b) explicit 2-deep double-buffered prefetch — k-step i+1's raw loads are
// issued before step i's MFMAs, all buffer indices compile-time constant
// under full unroll. blockIdx.z selects (A0,C0)/(A1,C1) for batched pos/neg.
// NOTE: A and C must NOT alias (cross-block race — r2..r4 lesson).
template<int ACT, int TRANS, int K, int NC, typename AT, typename OT>
__global__ __launch_bounds__(256)
void gemm_direct_k(const AT* __restrict__ A0, const AT* __restrict__ A1,
                   const _Float16* __restrict__ Wt, const float* __restrict__ tr,
                   OT* __restrict__ C0, OT* __restrict__ C1, int M)
{
  constexpr int NK = K / 32;
  const AT* A = blockIdx.z ? A1 : A0;
  OT* C = blockIdx.z ? C1 : C0;
  const int tid = threadIdx.x;
  const int lane = tid & 63;
  const int l15 = lane & 15, lg = lane >> 4;
  const int wave = tid >> 6;
  const int wm = wave >> 1, wn = wave & 1;
  const int bm = blockIdx.x * 64;
  const int bn = blockIdx.y * 128;
  f32x4 acc[2][4];
#pragma unroll
  for (int m = 0; m < 2; ++m)
#pragma unroll
    for (int n = 0; n < 4; ++n) acc[m][n] = (f32x4){0.f, 0.f, 0.f, 0.f};

  int arow[2];
#pragma unroll
  for (int m = 0; m < 2; ++m)
    arow[m] = min(bm + wm * 32 + m * 16 + l15, M - 1);   // clamp: loads always legal
  const int bcol = bn + wn * 64 + l15;

  half8  bBuf[2][4];       // B fragments, double-buffered
  float4 aRF[2][2][2];     // A raw (fp32 path)
  half8  aRH[2][2];        // A raw (fp16 path)

  // ---- prologue: k-step 0 -> buffer 0
  {
#pragma unroll
    for (int n = 0; n < 4; ++n)
      bBuf[0][n] = *(const half8*)&Wt[((size_t)lg * NC + bcol + n * 16) * 8];
    const int kb = lg * 8;
#pragma unroll
    for (int m = 0; m < 2; ++m) {
      if constexpr (sizeof(AT) == 4) {
        const float* ap = (const float*)A + (size_t)arow[m] * K + kb;
        aRF[0][m][0] = *(const float4*)ap;
        aRF[0][m][1] = *(const float4*)(ap + 4);
      } else {
        aRH[0][m] = *(const half8*)((const _Float16*)A + (size_t)arow[m] * K + kb);
      }
    }
  }

#pragma unroll
  for (int ks = 0; ks < NK; ++ks) {
    const int cur = ks & 1, nxt = cur ^ 1;
    // ---- issue k-step ks+1 loads into the other buffer (before MFMAs of ks)
    if (ks + 1 < NK) {
      const int kbn = (ks + 1) * 32 + lg * 8;
#pragma unroll
      for (int n = 0; n < 4; ++n)
        bBuf[nxt][n] = *(const half8*)&Wt[((size_t)((ks + 1) * 4 + lg) * NC + bcol + n * 16) * 8];
#pragma unroll
      for (int m = 0; m < 2; ++m) {
        if constexpr (sizeof(AT) == 4) {
          const float* ap = (const float*)A + (size_t)arow[m] * K + kbn;
          aRF[nxt][m][0] = *(const float4*)ap;
          aRF[nxt][m][1] = *(const float4*)(ap + 4);
        } else {
          aRH[nxt][m] = *(const half8*)((const _Float16*)A + (size_t)arow[m] * K + kbn);
        }
      }
    }
    // ---- convert current A raw -> fp16 frags (+ optional BN transform)
    const int kb0 = ks * 32 + lg * 8;
    half8 aF[2];
#pragma unroll
    for (int m = 0; m < 2; ++m) {
      half8 sa;
      if constexpr (sizeof(AT) == 4) {
        float va[8] = {aRF[cur][m][0].x, aRF[cur][m][0].y, aRF[cur][m][0].z, aRF[cur][m][0].w,
                       aRF[cur][m][1].x, aRF[cur][m][1].y, aRF[cur][m][1].z, aRF[cur][m][1].w};
        if constexpr (TRANS) {
#pragma unroll
          for (int j = 0; j < 8; ++j) va[j] = (va[j] - tr[kb0 + j]) * tr[256 + kb0 + j];
        }
#pragma unroll
        for (int j = 0; j < 8; ++j) sa[j] = (_Float16)va[j];
      } else {
        if constexpr (TRANS) {
#pragma unroll
          for (int j = 0; j < 8; ++j)
            sa[j] = (_Float16)(((float)aRH[cur][m][j] - tr[kb0 + j]) * tr[256 + kb0 + j]);
        } else {
          sa = aRH[cur][m];
        }
      }
      aF[m] = sa;
    }
#pragma unroll
    for (int m = 0; m < 2; ++m)
#pragma unroll
      for (int n = 0; n < 4; ++n)
        acc[m][n] = __builtin_amdgcn_mfma_f32_16x16x32_f16(aF[m], bBuf[cur][n], acc[m][n], 0, 0, 0);
  }
  // epilogue: C/D layout col=lane&15, row=(lane>>4)*4+q (stores guarded)
#pragma unroll
  for (int m = 0; m < 2; ++m) {
    int row_b = bm + wm * 32 + m * 16 + lg * 4;
#pragma unroll
    for (int q = 0; q < 4; ++q) {
      int row = row_b + q;
      if (row >= M) continue;
#pragma unroll
      for (int n = 0; n < 4; ++n) {
        float v = acc[m][n][q];
        if (ACT == 1) v = fmaxf(v, 0.f);
        else if (ACT == 2) v = 1.f / (1.f + expf(-v));
        C[(size_t)row * NC + bn + wn * 64 + n * 16 + l15] = (OT)v;
      }
    }
  }
}

// ======================= small-M tiled f32 GEMM (M<=1000 paths) =======================
template<int ACT>
__global__ __launch_bounds__(256)
void gemm_k(const float* __restrict__ A, const float* __restrict__ W,
            const float* __restrict__ bias, float* __restrict__ C,
            int M, int K, int Nc)
{
  __shared__ float As[32][136];
  __shared__ float Ws[32][68];
  const int tid = threadIdx.x;
  const int bm = blockIdx.x * 128;
  const int bn = blockIdx.y * 64;
  const int tm = (tid & 15) * 8;
  const int tn = (tid >> 4) * 4;
  float acc[8][4];
#pragma unroll
  for (int i = 0; i < 8; ++i)
#pragma unroll
    for (int j = 0; j < 4; ++j) acc[i][j] = 0.f;

  for (int k0 = 0; k0 < K; k0 += 32) {
#pragma unroll
    for (int l = 0; l < 4; ++l) {
      int idx = tid + l * 256;
      int r = idx >> 3;
      int kq = (idx & 7) << 2;
      int gr = bm + r;
      float4 v = make_float4(0.f, 0.f, 0.f, 0.f);
      if (gr < M) v = *(const float4*)&A[(size_t)gr * K + k0 + kq];
      As[kq + 0][r] = v.x; As[kq + 1][r] = v.y;
      As[kq + 2][r] = v.z; As[kq + 3][r] = v.w;
    }
#pragma unroll
    for (int l = 0; l < 2; ++l) {
      int idx = tid + l * 256;
      int r = idx >> 4;
      int nq = (idx & 15) << 2;
      *(float4*)&Ws[r][nq] = *(const float4*)&W[(size_t)(k0 + r) * Nc + bn + nq];
    }
    __syncthreads();
#pragma unroll
    for (int kk = 0; kk < 32; ++kk) {
      float4 a0 = *(float4*)&As[kk][tm];
      float4 a1 = *(float4*)&As[kk][tm + 4];
      float4 w4 = *(float4*)&Ws[kk][tn];
      float am[8] = {a0.x, a0.y, a0.z, a0.w, a1.x, a1.y, a1.z, a1.w};
      float wn4[4] = {w4.x, w4.y, w4.z, w4.w};
#pragma unroll
      for (int i = 0; i < 8; ++i)
#pragma unroll
        for (int j = 0; j < 4; ++j) acc[i][j] += am[i] * wn4[j];
    }
    __syncthreads();
  }
  float4 bv = make_float4(0.f, 0.f, 0.f, 0.f);
  if (bias) bv = *(const float4*)&bias[bn + tn];
#pragma unroll
  for (int i = 0; i < 8; ++i) {
    int row = bm + tm + i;
    if (row >= M) break;
    float o0 = acc[i][0] + bv.x, o1 = acc[i][1] + bv.y;
    float o2 = acc[i][2] + bv.z, o3 = acc[i][3] + bv.w;
    if (ACT == 1) {
      o0 = fmaxf(o0, 0.f); o1 = fmaxf(o1, 0.f);
      o2 = fmaxf(o2, 0.f); o3 = fmaxf(o3, 0.f);
    } else if (ACT == 2) {
      o0 = 1.f / (1.f + expf(-o0)); o1 = 1.f / (1.f + expf(-o1));
      o2 = 1.f / (1.f + expf(-o2)); o3 = 1.f / (1.f + expf(-o3));
    }
    *(float4*)&C[(size_t)row * Nc + bn + tn] = make_float4(o0, o1, o2, o3);
  }
}

// ================= per-graph GCN aggregation, MFMA (fused tails) =================
// Integer-count adjacency build (deterministic), fp16 Adh; W=128 stages H
// transposed in LDS. See r10/r11 notes. blockIdx.y selects pos/neg.
template<int W, int ACT, int SEGBN, int L2N, int POOL, int STATS, int MAXP, typename OT>
__global__ __launch_bounds__(512)
void gcn_agg_k(const _Float16* __restrict__ H0, const _Float16* __restrict__ H1,
               const int* __restrict__ src0, const int* __restrict__ src1,
               const int* __restrict__ dst0, const int* __restrict__ dst1,
               const float* __restrict__ bias,
               OT* __restrict__ OUT0, OT* __restrict__ OUT1, int epg,
               const float* __restrict__ NOI, float* __restrict__ PST,
               float* __restrict__ ZG, float* __restrict__ ZZ)
{
  extern __shared__ __align__(16) unsigned lds_u[];
  unsigned* cnt32 = lds_u;                                   // [112][33] u32
  _Float16* Adh = (_Float16*)(lds_u + 112 * kCntW);          // [112][136]
  _Float16* Hst = (_Float16*)((char*)lds_u + 45248);         // [128][136] (W=128)
  float* scr = (float*)lds_u;                                // post-MFMA scratch
  __shared__ int scnt[kNPG];
  __shared__ float sdinv[kNPG];
  const _Float16* H = blockIdx.y ? H1 : H0;
  const int* srcI = blockIdx.y ? src1 : src0;
  const int* dstI = blockIdx.y ? dst1 : dst0;
  OT* OUT = blockIdx.y ? OUT1 : OUT0;
  const int g = blockIdx.x, tid = threadIdx.x;
  const int base = g * kNPG;
  const size_t ebase = (size_t)g * epg;
  const int lane = tid & 63, wv = tid >> 6;
  const int l15 = lane & 15, lg = lane >> 4;

  for (int i = tid; i < 112 * kCntW; i += 512) cnt32[i] = 0u;
  if constexpr (W == 128) {
    for (int i = tid; i < 128 * 18; i += 512) {
      int c = i / 18, w = i - c * 18;
      ((unsigned*)&Hst[c * kAhS + 100])[w] = 0u;
    }
  }
  if (tid < kNPG) scnt[tid] = 0;
  __syncthreads();
  for (int e = tid; e < epg; e += 512) {
    int s = srcI[ebase + e] - base;
    int d = dstI[ebase + e] - base;
    atomicAdd(&scnt[d], 1);
    atomicAdd(&cnt32[d * kCntW + (s >> 2)], 1u << (8 * (s & 3)));
  }
  __syncthreads();
  if (tid < kNPG) sdinv[tid] = rsqrtf((float)scnt[tid] + 1.f);
  __syncthreads();
  for (int i = tid; i < 112 * kAhS; i += 512) {
    int d = i / kAhS, s = i - d * kAhS;
    float v = 0.f;
    if (d < 100 && s < 100) {
      unsigned w = cnt32[d * kCntW + (s >> 2)];
      unsigned c = (w >> (8 * (s & 3))) & 0xFFu;
      c += (s == d) ? 1u : 0u;
      v = (float)c * sdinv[s] * sdinv[d];
    }
    Adh[i] = (_Float16)v;
  }
  if constexpr (W == 128) {
    const int c = tid & 127;
    for (int j = tid >> 7; j < 100; j += 4)
      Hst[c * kAhS + j] = H[(size_t)(base + j) * 128 + c];
  }
  __syncthreads();

  if constexpr (W == 256) {
    const int cbase = wv * 32;
    f32x4 acc[7][2];
#pragma unroll
    for (int mt = 0; mt < 7; ++mt) {
      acc[mt][0] = (f32x4){0.f, 0.f, 0.f, 0.f};
      acc[mt][1] = (f32x4){0.f, 0.f, 0.f, 0.f};
    }
#pragma unroll
    for (int k0 = 0; k0 < 128; k0 += 32) {
      const int kb = k0 + lg * 8;
      half8 bF[2];
#pragma unroll
      for (int t = 0; t < 2; ++t) {
        int col = cbase + t * 16 + l15;
#pragma unroll
        for (int e = 0; e < 8; ++e) {
          int row = min(base + kb + e, kN - 1);   // clamp: Adh=0 past 100
          bF[t][e] = H[(size_t)row * W + col];
        }
      }
#pragma unroll
      for (int mt = 0; mt < 7; ++mt) {
        half8 aF = *(const half8*)&Adh[(mt * 16 + l15) * kAhS + kb];
        acc[mt][0] = __builtin_amdgcn_mfma_f32_16x16x32_f16(aF, bF[0], acc[mt][0], 0, 0, 0);
        acc[mt][1] = __builtin_amdgcn_mfma_f32_16x16x32_f16(aF, bF[1], acc[mt][1], 0, 0, 0);
      }
    }
    float bv0 = bias ? bias[cbase + l15] : 0.f;
    float bv1 = bias ? bias[cbase + 16 + l15] : 0.f;
#pragma unroll
    for (int mt = 0; mt < 7; ++mt)
#pragma unroll
      for (int q = 0; q < 4; ++q) {
        float v0 = acc[mt][0][q] + bv0, v1 = acc[mt][1][q] + bv1;
        if (ACT == 1) { v0 = fmaxf(v0, 0.f); v1 = fmaxf(v1, 0.f); }
        acc[mt][0][q] = v0; acc[mt][1][q] = v1;
      }
    if constexpr (SEGBN || STATS) {
      float s0 = 0.f, s20 = 0.f, s1 = 0.f, s21 = 0.f;
#pragma unroll
      for (int mt = 0; mt < 7; ++mt)
#pragma unroll
        for (int q = 0; q < 4; ++q) {
          int row = mt * 16 + lg * 4 + q;
          if (row < 100) {
            float v0 = acc[mt][0][q], v1 = acc[mt][1][q];
            s0 += v0; s20 += v0 * v0; s1 += v1; s21 += v1 * v1;
          }
        }
      s0 += __shfl_xor(s0, 16, 64);  s0 += __shfl_xor(s0, 32, 64);
      s20 += __shfl_xor(s20, 16, 64); s20 += __shfl_xor(s20, 32, 64);
      s1 += __shfl_xor(s1, 16, 64);  s1 += __shfl_xor(s1, 32, 64);
      s21 += __shfl_xor(s21, 16, 64); s21 += __shfl_xor(s21, 32, 64);
      if constexpr (STATS) {
        if (lg == 0) {
          PST[(size_t)g * 512 + cbase + l15] = s0;
          PST[(size_t)g * 512 + 256 + cbase + l15] = s20;
          PST[(size_t)g * 512 + cbase + 16 + l15] = s1;
          PST[(size_t)g * 512 + 256 + cbase + 16 + l15] = s21;
        }
      }
      if constexpr (SEGBN) {
        float m0 = s0 / 100.f, r0 = rsqrtf(s20 / 100.f - m0 * m0 + BN_EPS);
        float m1 = s1 / 100.f, r1 = rsqrtf(s21 / 100.f - m1 * m1 + BN_EPS);
#pragma unroll
        for (int mt = 0; mt < 7; ++mt)
#pragma unroll
          for (int q = 0; q < 4; ++q) {
            acc[mt][0][q] = (acc[mt][0][q] - m0) * r0;
            acc[mt][1][q] = (acc[mt][1][q] - m1) * r1;
          }
      }
    }
#pragma unroll
    for (int mt = 0; mt < 7; ++mt)
#pragma unroll
      for (int q = 0; q < 4; ++q) {
        int row = mt * 16 + lg * 4 + q;
        if (row < 100) {
          OUT[(size_t)(base + row) * W + cbase + l15] = (OT)acc[mt][0][q];
          OUT[(size_t)(base + row) * W + cbase + 16 + l15] = (OT)acc[mt][1][q];
        }
      }
  } else {
    const int mt = wv;                 // waves 0..6 active
    f32x4 acc[8];
#pragma unroll
    for (int nt = 0; nt < 8; ++nt) acc[nt] = (f32x4){0.f, 0.f, 0.f, 0.f};
    if (mt < 7) {
#pragma unroll
      for (int k0 = 0; k0 < 128; k0 += 32) {
        const int kb = k0 + lg * 8;
        half8 aF = *(const half8*)&Adh[(mt * 16 + l15) * kAhS + kb];
#pragma unroll
        for (int nt = 0; nt < 8; ++nt) {
          half8 bF = *(const half8*)&Hst[(nt * 16 + l15) * kAhS + kb];
          acc[nt] = __builtin_amdgcn_mfma_f32_16x16x32_f16(aF, bF, acc[nt], 0, 0, 0);
        }
      }
#pragma unroll
      for (int nt = 0; nt < 8; ++nt) {
        float bvn = bias ? bias[nt * 16 + l15] : 0.f;
#pragma unroll
        for (int q = 0; q < 4; ++q) {
          float v = acc[nt][q] + bvn;
          if (ACT == 1) v = fmaxf(v, 0.f);
          acc[nt][q] = v;
        }
      }
      if constexpr (L2N) {
#pragma unroll
        for (int q = 0; q < 4; ++q) {
          float ss = 0.f;
#pragma unroll
          for (int nt = 0; nt < 8; ++nt) ss += acc[nt][q] * acc[nt][q];
          ss += __shfl_xor(ss, 1, 64); ss += __shfl_xor(ss, 2, 64);
          ss += __shfl_xor(ss, 4, 64); ss += __shfl_xor(ss, 8, 64);
          float inv = 1.f / fmaxf(sqrtf(ss), 1e-12f);
#pragma unroll
          for (int nt = 0; nt < 8; ++nt) acc[nt][q] *= inv;
        }
      }
      if constexpr (!POOL) {
#pragma unroll
        for (int nt = 0; nt < 8; ++nt)
#pragma unroll
          for (int q = 0; q < 4; ++q) {
            int row = mt * 16 + lg * 4 + q;
            if (row < 100)
              OUT[(size_t)(base + row) * W + nt * 16 + l15] = (OT)acc[nt][q];
          }
      }
    }
    if constexpr (POOL) {
      float ps[8];
#pragma unroll
      for (int nt = 0; nt < 8; ++nt) ps[nt] = 0.f;
      if (mt < 7) {
#pragma unroll
        for (int nt = 0; nt < 8; ++nt)
#pragma unroll
          for (int q = 0; q < 4; ++q) {
            int row = mt * 16 + lg * 4 + q;
            if (row < 100) ps[nt] += acc[nt][q];
          }
      }
#pragma unroll
      for (int nt = 0; nt < 8; ++nt) {
        ps[nt] += __shfl_xor(ps[nt], 16, 64);
        ps[nt] += __shfl_xor(ps[nt], 32, 64);
      }
      __syncthreads();                  // cnt32/Adh dead -> scratch
      if (mt < 7 && lg == 0)
#pragma unroll
        for (int nt = 0; nt < 8; ++nt) scr[wv * 128 + nt * 16 + l15] = ps[nt];
      __syncthreads();
      if (tid < 128) {
        float s = 0.f;
        for (int w2 = 0; w2 < 7; ++w2) s += scr[w2 * 128 + tid];
        OUT[(size_t)g * W + tid] = (OT)(s / 100.f);
      }
    }
    if constexpr (MAXP) {
      float m1[8], m2[8];
#pragma unroll
      for (int nt = 0; nt < 8; ++nt) { m1[nt] = -INFINITY; m2[nt] = -INFINITY; }
      if (mt < 7) {
#pragma unroll
        for (int nt = 0; nt < 8; ++nt)
#pragma unroll
          for (int q = 0; q < 4; ++q) {
            int row = mt * 16 + lg * 4 + q;
            if (row < 100) {
              float zv = acc[nt][q];
              float nv = NOI[(size_t)(base + row) * 128 + nt * 16 + l15];
              m1[nt] = fmaxf(m1[nt], zv);
              m2[nt] = fmaxf(m2[nt], zv + nv);
            }
          }
#pragma unroll
        for (int nt = 0; nt < 8; ++nt) {
          m1[nt] = fmaxf(m1[nt], __shfl_xor(m1[nt], 16, 64));
          m1[nt] = fmaxf(m1[nt], __shfl_xor(m1[nt], 32, 64));
          m2[nt] = fmaxf(m2[nt], __shfl_xor(m2[nt], 16, 64));
          m2[nt] = fmaxf(m2[nt], __shfl_xor(m2[nt], 32, 64));
        }
      }
      __syncthreads();                  // cnt32/Adh dead -> scratch
      if (mt < 7 && lg == 0)
#pragma unroll
        for (int nt = 0; nt < 8; ++nt) {
          scr[wv * 128 + nt * 16 + l15] = m1[nt];
          scr[1024 + wv * 128 + nt * 16 + l15] = m2[nt];
        }
      __syncthreads();
      if (tid < 128) {
        float a = -INFINITY, b = -INFINITY;
        for (int w2 = 0; w2 < 7; ++w2) {
          a = fmaxf(a, scr[w2 * 128 + tid]);
          b = fmaxf(b, scr[1024 + w2 * 128 + tid]);
        }
        ZG[(size_t)g * 128 + tid] = a;
        ZZ[(size_t)g * 128 + tid] = a;
        ZZ[(size_t)(500 + g) * 128 + tid] = b;
      }
    }
  }
}

// ============ BN finalize: sum 500 per-graph partials (fixed order) ============
__global__ __launch_bounds__(256)
void bn_red_k(const float* __restrict__ P, float* __restrict__ stats)
{
  const int c = threadIdx.x;
  float s = 0.f, s2 = 0.f;
  for (int b = 0; b < 500; ++b) {
    s  += P[(size_t)b * 512 + c];
    s2 += P[(size_t)b * 512 + 256 + c];
  }
  float m = s / (float)kN;
  float v = s2 / (float)kN - m * m;
  stats[512 + c] = m;
  stats[768 + c] = rsqrtf(v + BN_EPS);
}

// column-parallel BN, in place (target path)
__global__ __launch_bounds__(64)
void bn_cols_k(float* __restrict__ X, int rows, int cols)
{
  const int c = blockIdx.x, t = threadIdx.x;
  float s = 0.f, s2 = 0.f;
  for (int r = t; r < rows; r += 64) {
    float v = X[(size_t)r * cols + c];
    s += v; s2 += v * v;
  }
#pragma unroll
  for (int o = 32; o; o >>= 1) { s += __shfl_xor(s, o, 64); s2 += __shfl_xor(s2, o, 64); }
  float m = s / (float)rows;
  float var = s2 / (float)rows - m * m;
  float rinv = rsqrtf(var + BN_EPS);
  for (int r = t; r < rows; r += 64)
    X[(size_t)r * cols + c] = (X[(size_t)r * cols + c] - m) * rinv;
}

// row-wise L2 normalize (128 cols) — target path
__global__ __launch_bounds__(256)
void l2n_k(const float* __restrict__ X, float* __restrict__ Y, int rows)
{
  const int w = threadIdx.x >> 6, lane = threadIdx.x & 63;
  const int row = blockIdx.x * 4 + w;
  if (row >= rows) return;
  float2 v = *(const float2*)&X[(size_t)row * kH2 + lane * 2];
  float ss = v.x * v.x + v.y * v.y;
#pragma unroll
  for (int o = 32; o; o >>= 1) ss += __shfl_xor(ss, o, 64);
  float inv = 1.f / fmaxf(sqrtf(ss), 1e-12f);
  *(float2*)&Y[(size_t)row * kH2 + lane * 2] = make_float2(v.x * inv, v.y * inv);
}

// =========================================================================
extern "C" void kernel_launch(void* const* d_in, const int* in_sizes, int n_in,
                              void* d_out, int out_size, void* d_ws, size_t ws_size,
                              hipStream_t stream)
{
  const float* x        = (const float*)d_in[0];
  const int*   srcI     = (const int*)d_in[1];
  const int*   dstI     = (const int*)d_in[2];
  const float* pos_x    = (const float*)d_in[4];
  const int*   psrc     = (const int*)d_in[5];
  const int*   pdst     = (const int*)d_in[6];
  const float* neg_x    = (const float*)d_in[8];
  const int*   nsrc     = (const int*)d_in[9];
  const int*   ndst     = (const int*)d_in[10];
  const float* target_x = (const float*)d_in[12];
  const float* noise    = (const float*)d_in[13];
  const float* W_enc1   = (const float*)d_in[14];
  const float* b_enc1   = (const float*)d_in[15];
  const float* W_enc2   = (const float*)d_in[16];
  const float* b_enc2   = (const float*)d_in[17];
  const float* W_dec1   = (const float*)d_in[18];
  const float* W_dec2   = (const float*)d_in[19];
  const float* Wn1      = (const float*)d_in[20];
  const float* bn1      = (const float*)d_in[21];
  const float* Wn2      = (const float*)d_in[22];
  const float* bn2      = (const float*)d_in[23];
  const float* Ws1      = (const float*)d_in[24];
  const float* bs1      = (const float*)d_in[25];
  const float* Wp1      = (const float*)d_in[26];
  const float* bp1      = (const float*)d_in[27];
  const float* Wp2      = (const float*)d_in[28];
  const float* bp2      = (const float*)d_in[29];

  float* out  = (float*)d_out;
  float* o_z   = out;                 // N x 128
  float* o_zg  = out + 6400000;       // 500 x 128
  float* o_xr  = out + 6464000;       // N x 128
  float* o_pos = out + 12864000;      // 500 x 128
  float* o_neg = out + 12928000;
  float* o_zgm = out + 12992000;      // o_zgm||o_zpm contiguous 1000 x 128
  float* o_tz  = out + 13120000;

  // WORKSPACE MAP (float offsets). Four 6.4M-float quarters Q0..Q3 hold fp16
  // N x 256 regions; every kernel reads one region and writes another
  // (r2-r4 race lesson). Time-multiplexed aliases audited per launch below.
  float* ws = (float*)d_ws;
  _Float16* hA    = (_Float16*)ws;                    // Q0
  _Float16* hC    = (_Float16*)ws;                    // Q0 (N x 128)
  _Float16* hDec  = (_Float16*)ws;                    // Q0
  _Float16* hAn   = (_Float16*)(ws + 6400000);        // Q1
  _Float16* hCn   = (_Float16*)(ws + 6400000);        // Q1
  _Float16* hB    = (_Float16*)(ws + 12800000);       // Q2
  _Float16* hBn   = (_Float16*)(ws + 19200000);       // Q3
  float* pstat = ws + 19200000;                       // Q3 (main-time only)
  _Float16* hWt   = (_Float16*)(ws + 25600000);       // 163840 fp16
  float* stats = ws + 25700000;                       // 1024
  float* zz    = ws + 6400000;                        // Q1 (main/proj-time)
  float* t1000 = ws + 6600000;                        // Q1 (proj-time)
  float* t1    = ws + 4000000;                        // Q0 tail (target-time)
  float* t2    = ws + 4200000;                        // Q0 tail (target-time)
  if (ws_size < (size_t)(25921024) * sizeof(float)) return;

  _Float16* WtEnc1 = hWt;
  _Float16* WtEnc2 = hWt + 32768;
  _Float16* WtDec1 = hWt + 65536;
  _Float16* WtDec2 = hWt + 98304;
  _Float16* WtS1   = hWt + 131072;

  (void)hipFuncSetAttribute((const void*)gcn_agg_k<128, 0, 0, 1, 0, 0, 1, float>,
      hipFuncAttributeMaxDynamicSharedMemorySize, kAggLds128);
  (void)hipFuncSetAttribute((const void*)gcn_agg_k<128, 0, 0, 1, 1, 0, 0, float>,
      hipFuncAttributeMaxDynamicSharedMemorySize, kAggLds128);

  const dim3 gB1(782, 2, 1);   // M=50000 (64-row tiles), Nc=256, single
  const dim3 gC1(782, 1, 1);   // Nc=128, single
  const dim3 gB2(782, 2, 2);   // batched pos+neg
  const dim3 gC2(782, 1, 2);
  auto gg = [](int M, int Nc) {
    return dim3((unsigned)((M + 127) / 128), (unsigned)(Nc / 64), 1);
  };

  // ---------------- weight prep ----------------
  wprep_k<<<640, 256, 0, stream>>>(W_enc1, W_enc2, W_dec1, W_dec2, Ws1, hWt);

  // ---------------- main encode ----------------
  gemm_direct_k<0, 0, 128, 256, float, _Float16><<<gB1, 256, 0, stream>>>(x, x, WtEnc1, nullptr, hA, hA, kN);
  // agg256+STATS: reads hA(Q0) -> writes hB(Q2) + pstat(Q3)
  gcn_agg_k<256, 1, 0, 0, 0, 1, 0, _Float16><<<dim3(kB, 1), 512, kAggLds256, stream>>>(
      hA, hA, srcI, srcI, dstI, dstI, b_enc1, hB, hB, kEPG, nullptr, pstat, nullptr, nullptr);
  bn_red_k<<<1, 256, 0, stream>>>(pstat, stats);
  // G2+BN: reads hB(Q2)+stats -> writes hC(Q0)
  gemm_direct_k<0, 1, 256, 128, _Float16, _Float16><<<gC1, 256, 0, stream>>>(hB, hB, WtEnc2, stats + 512, hC, hC, kN);
  // agg128+L2N+MAXP: reads hC(Q0)+noise -> writes o_z, o_zg, zz(Q1)
  gcn_agg_k<128, 0, 0, 1, 0, 0, 1, float><<<dim3(kB, 1), 512, kAggLds128, stream>>>(
      hC, hC, srcI, srcI, dstI, dstI, b_enc2, o_z, o_z, kEPG, noise, nullptr, o_zg, zz);
  // decode: o_z(d_out) -> hDec(Q0) -> o_xr(d_out)
  gemm_direct_k<1, 0, 128, 256, float, _Float16><<<gB1, 256, 0, stream>>>(o_z, o_z, WtDec1, nullptr, hDec, hDec, kN);
  gemm_direct_k<2, 0, 256, 128, _Float16, float><<<gC1, 256, 0, stream>>>(hDec, hDec, WtDec2, nullptr, o_xr, o_xr, kN);
  // merged projection heads: zz(Q1) -> t1000(Q1') -> o_zgm||o_zpm
  gemm_k<1><<<gg(1000, kH2), 256, 0, stream>>>(zz, Wp1, bp1, t1000, 1000, kH2, kH2);
  gemm_k<0><<<gg(1000, kH2), 256, 0, stream>>>(t1000, Wp2, bp2, o_zgm, 1000, kH2, kH2);

  // ---------------- pos + neg, batched ----------------
  gemm_direct_k<0, 0, 128, 256, float, _Float16><<<gB2, 256, 0, stream>>>(pos_x, neg_x, WtS1, nullptr, hA, hAn, kN);
  gcn_agg_k<256, 1, 1, 0, 0, 0, 0, _Float16><<<dim3(kB, 2), 512, kAggLds256, stream>>>(
      hA, hAn, psrc, nsrc, pdst, ndst, bs1, hB, hBn, kESG, nullptr, nullptr, nullptr, nullptr);
  gemm_direct_k<0, 0, 256, 128, _Float16, _Float16><<<gC2, 256, 0, stream>>>(hB, hBn, WtEnc2, nullptr, hC, hCn, kN);
  gcn_agg_k<128, 0, 0, 1, 1, 0, 0, float><<<dim3(kB, 2), 512, kAggLds128, stream>>>(
      hC, hCn, psrc, nsrc, pdst, ndst, b_enc2, o_pos, o_neg, kESG, nullptr, nullptr, nullptr, nullptr);

  // ---------------- target node encoder ----------------
  gemm_k<1><<<gg(kB, kH1), 256, 0, stream>>>(target_x, Wn1, bn1, t1, kB, kF0, kH1);
  bn_cols_k<<<256, 64, 0, stream>>>(t1, kB, kH1);
  gemm_k<0><<<gg(kB, kH2), 256, 0, stream>>>(t1, Wn2, bn2, t2, kB, kH1, kH2);
  l2n_k<<<125, 256, 0, stream>>>(t2, o_tz, kB);

  (void)in_sizes; (void)n_in; (void)out_size;
}